// Round 3
// baseline (290.524 us; speedup 1.0000x reference)
//
#include <hip/hip_runtime.h>
#include <math.h>

// GradLoss over (B=8, C=4, D=64, H=128, W=128) fp32 tensors.
// out = sum over axes {D,H,W} of sum_c mean_{b,d,h,w} (grad(x)-grad(t))^2
// (clean() dropped: |g|<1e-6 zeroing perturbs the total ~1e-9; absmax 0.0.)
//
// R7: latency-parallelism fix, take 2. R4 (6 loads/step, register-only) and
// R6 (2 loads/step + LDS + barrier) both plateau at ~110us / 1.9 TB/s -- the
// wave stalls a full HBM latency every h-step because loads are consumed in
// the iteration they are issued (R4) or drained by __syncthreads (R6). R5's
// accidental evidence: with more requests in flight the same layout sustains
// 3.2 TB/s. So: barrier-free register structure + explicit 1-step-ahead
// software pipeline. Iteration hl issues all 6 loads for step hl+1 into a
// ping-pong register buffer (compile-time indexed under full unroll -> stays
// in VGPRs), then consumes step hl's already-landed values. Load->use
// distance = one full iteration; 6-12 loads per wave continuously in flight;
// vmcnt never drains. No launch_bounds min-waves clamp (R5 spill lesson).

#define Bn 8
#define Cn 4
#define Dn 64
#define Hn 128
#define Wn 128

static constexpr int HCHUNK = 8;             // h-steps per thread
static constexpr int NTHREADS = 256;         // w4(32) x dlow(8)
static constexpr int NBLOCKS = 4096;         // bc(32) x hc(16) x dhigh(8)
static constexpr int ROW = Wn / 4;           // 32 float4 per W-row
static constexpr int PLANE = Hn * ROW;       // 4096 float4 per (H,W) plane

__device__ __forceinline__ float4 sub4(const float4 a, const float4 b) {
    float4 r;
    r.x = a.x - b.x; r.y = a.y - b.y;
    r.z = a.z - b.z; r.w = a.w - b.w;
    return r;
}

struct Step {
    float4 xp, tp;      // center row at h+1 (H-window feed)
    float4 xdp, tdp;    // d+1 plane, row h
    float4 xdm, tdm;    // d-1 plane, row h
};

__device__ __forceinline__ void issue_step(
        const float4* __restrict__ Xr, const float4* __restrict__ Tr,
        int po, int dpo, int dmo, Step& s) {
    s.xp  = Xr[po];  s.tp  = Tr[po];
    s.xdp = Xr[dpo]; s.tdp = Tr[dpo];
    s.xdm = Xr[dmo]; s.tdm = Tr[dmo];
}

__global__ __launch_bounds__(NTHREADS) void gradloss_main(
        const float* __restrict__ xf, const float* __restrict__ tf,
        double* __restrict__ partials) {
    const int tid  = threadIdx.x;
    const int w4   = tid & 31;          // float4 index within W-row
    const int dlow = tid >> 5;          // 8 consecutive d-planes (L1 reuse of d+-1 rows)
    const int b    = blockIdx.x;
    const int bc    = b & 31;           // low bits -> XCD slab ownership
    const int hc    = (b >> 5) & 15;
    const int dhigh = b >> 9;
    const int d  = dhigh * 8 + dlow;
    const int h0 = hc * HCHUNK;

    const int base = ((bc * Dn + d) * Hn + h0) * ROW + w4;  // float4 index
    const float4* __restrict__ Xr = (const float4*)xf + base;
    const float4* __restrict__ Tr = (const float4*)tf + base;

    const int dpo = (d < Dn - 1) ? PLANE : 0;
    const int dmo = (d > 0) ? -PLANE : 0;
    const float sd2  = (d == 0 || d == Dn - 1) ? 1.0f : 0.25f;
    const float sw02 = (w4 == 0) ? 1.0f : 0.25f;
    const float sw32 = (w4 == 31) ? 1.0f : 0.25f;

    // ---- prologue: issue H-window loads + step-0 loads back-to-back ----
    const int mo = (h0 > 0) ? -ROW : 0;      // block-uniform
    const float4 xc0 = Xr[0],  tc0 = Tr[0];
    const float4 xm0 = Xr[mo], tm0 = Tr[mo];
    Step sbuf[2];
    {
        // h0 <= 120, so h0 < Hn-1 always: po = ROW for step 0
        issue_step(Xr, Tr, ROW, dpo, dmo, sbuf[0]);
    }
    float4 uc = sub4(xc0, tc0);
    float4 um = sub4(xm0, tm0);              // h0==0: mo=0 -> um == uc (one-sided)

    float acc0 = 0.0f, acc1 = 0.0f, acc2 = 0.0f;
    #pragma unroll
    for (int hl = 0; hl < HCHUNK; ++hl) {
        const int h = h0 + hl;

        // ---- issue step hl+1 (lands while we compute step hl) ----
        if (hl + 1 < HCHUNK) {
            const int po2 = (h + 1 < Hn - 1) ? ROW : 0;   // block-uniform
            issue_step(Xr + ROW, Tr + ROW, po2, dpo, dmo, sbuf[(hl + 1) & 1]);
        }

        // ---- consume step hl (issued last iteration) ----
        const Step& s = sbuf[hl & 1];

        // D axis: diff = sd*((x(d+1)-x(d-1)) - (t(d+1)-t(d-1))) at row h
        { const float dx = (s.xdp.x - s.xdm.x) - (s.tdp.x - s.tdm.x); acc1 = fmaf(dx * dx, sd2, acc1); }
        { const float dx = (s.xdp.y - s.xdm.y) - (s.tdp.y - s.tdm.y); acc1 = fmaf(dx * dx, sd2, acc1); }
        { const float dx = (s.xdp.z - s.xdm.z) - (s.tdp.z - s.tdm.z); acc1 = fmaf(dx * dx, sd2, acc1); }
        { const float dx = (s.xdp.w - s.xdm.w) - (s.tdp.w - s.tdm.w); acc1 = fmaf(dx * dx, sd2, acc1); }

        // W axis: neighbors via shfl on u(h) within 32-lane groups
        const float ulw = __shfl_up(uc.w, 1, 32);
        const float urx = __shfl_down(uc.x, 1, 32);
        const float ul = (w4 == 0)  ? uc.x : ulw;
        const float ur = (w4 == 31) ? uc.w : urx;
        { const float dx = uc.y - ul;   acc2 = fmaf(dx * dx, sw02, acc2); }
        { const float dx = uc.z - uc.x; acc2 = fmaf(dx * dx, 0.25f, acc2); }
        { const float dx = uc.w - uc.y; acc2 = fmaf(dx * dx, 0.25f, acc2); }
        { const float dx = ur - uc.z;   acc2 = fmaf(dx * dx, sw32, acc2); }

        // H axis: u(h+1) - u(h-1) in registers
        const float4 un = sub4(s.xp, s.tp);
        const float sh2 = (h == 0 || h == Hn - 1) ? 1.0f : 0.25f;
        { const float dx = un.x - um.x; acc0 = fmaf(dx * dx, sh2, acc0); }
        { const float dx = un.y - um.y; acc0 = fmaf(dx * dx, sh2, acc0); }
        { const float dx = un.z - um.z; acc0 = fmaf(dx * dx, sh2, acc0); }
        { const float dx = un.w - um.w; acc0 = fmaf(dx * dx, sh2, acc0); }

        // slide H window
        um = uc; uc = un;
        Xr += ROW; Tr += ROW;
    }

    float acc = (acc0 + acc1) + acc2;

    // wave (64-lane) reduction
    for (int off = 32; off > 0; off >>= 1)
        acc += __shfl_down(acc, off, 64);

    __shared__ float wsum[NTHREADS / 64];
    const int lane = tid & 63;
    const int wid = tid >> 6;
    if (lane == 0) wsum[wid] = acc;
    __syncthreads();
    if (tid == 0) {
        double bsum = (double)wsum[0] + (double)wsum[1] +
                      (double)wsum[2] + (double)wsum[3];
        partials[blockIdx.x] = bsum;
    }
}

__global__ __launch_bounds__(256) void gradloss_reduce(
        const double* __restrict__ partials, float* __restrict__ out, int n) {
    double a = 0.0;
    for (int i = threadIdx.x; i < n; i += 256) a += partials[i];
    for (int off = 32; off > 0; off >>= 1)
        a += __shfl_down(a, off, 64);
    __shared__ double sh[4];
    const int lane = threadIdx.x & 63;
    const int wid = threadIdx.x >> 6;
    if (lane == 0) sh[wid] = a;
    __syncthreads();
    if (threadIdx.x == 0) {
        double tot = sh[0] + sh[1] + sh[2] + sh[3];
        out[0] = (float)(tot / 8388608.0);  // / (B*D*H*W)
    }
}

extern "C" void kernel_launch(void* const* d_in, const int* in_sizes, int n_in,
                              void* d_out, int out_size, void* d_ws, size_t ws_size,
                              hipStream_t stream) {
    const float* x = (const float*)d_in[0];
    const float* t = (const float*)d_in[1];
    float* out = (float*)d_out;
    double* partials = (double*)d_ws;  // NBLOCKS * 8 B = 32 KiB of d_ws

    gradloss_main<<<NBLOCKS, NTHREADS, 0, stream>>>(x, t, partials);
    gradloss_reduce<<<1, 256, 0, stream>>>(partials, out, NBLOCKS);
}

// Round 4
// 280.458 us; speedup vs baseline: 1.0359x; 1.0359x over previous
//
#include <hip/hip_runtime.h>
#include <math.h>

// GradLoss over (B=8, C=4, D=64, H=128, W=128) fp32 tensors.
// out = sum over axes {D,H,W} of sum_c mean_{b,d,h,w} (grad(x)-grad(t))^2
// (clean() dropped: |g|<1e-6 zeroing perturbs the total ~1e-9; absmax 0.0.)
//
// R8: burst-load restructure. R4/R6/R7 all plateau at 105-111us / 1.8 TB/s
// with nothing saturated (VALU 11%, occ 48%, FETCH < compulsory -> L3-
// resident): pure latency limit because loads are dribbled 2-6 at a time
// with a consumer or barrier right behind them. R5's accidental spill proved
// the memory system does 3.2 TB/s on this layout when requests are queued
// deep. So: separate load phase from compute phase.
//   load phase: each thread bursts 24 independent global_load_dwordx4
//     (its own 10 h-rows of x,t + a share of the d-halo) -- no consumers
//     interleaved, vmcnt runs deep.
//   publish: u = x - t once; interior + d-halo u rows -> 40KB LDS tile.
//     ONE barrier total (R6 had 8).
//   compute phase: H-grad from the register window u[10], W-grad via shfl,
//     D-grad from LDS (2 ds_read_b128/step). Zero global latency exposure.
// LDS reused for the wave-sum scratch to stay at exactly 40960B (4 blk/CU).
// No launch_bounds min-waves clamp (R5 spill lesson) -- VGPR may be ~140.

#define Bn 8
#define Cn 4
#define Dn 64
#define Hn 128
#define Wn 128

static constexpr int NTHREADS = 256;         // dlow(8) x w4(32)
static constexpr int NBLOCKS = 4096;         // bc(32) x hc(16) x dtile(8)
static constexpr int ROW = Wn / 4;           // 32 float4 per W-row
static constexpr int PLANE = Hn * ROW;       // 4096 float4 per (H,W) plane

__device__ __forceinline__ float4 sub4(const float4 a, const float4 b) {
    float4 r;
    r.x = a.x - b.x; r.y = a.y - b.y;
    r.z = a.z - b.z; r.w = a.w - b.w;
    return r;
}

__global__ __launch_bounds__(NTHREADS) void gradloss_main(
        const float* __restrict__ xf, const float* __restrict__ tf,
        double* __restrict__ partials) {
    const int tid  = threadIdx.x;
    const int w4   = tid & 31;          // float4 index within W-row
    const int dlow = tid >> 5;          // 8 d-planes per block
    const int b    = blockIdx.x;
    const int bc    = b & 31;           // low bits -> XCD slab ownership
    const int hc    = (b >> 5) & 15;
    const int dt    = b >> 9;
    const int d  = dt * 8 + dlow;
    const int h0 = hc * 8;

    const float4* __restrict__ X = (const float4*)xf;
    const float4* __restrict__ T = (const float4*)tf;
    const int slab  = bc * (Dn * PLANE);        // max index ~4.2M: fits int
    const int pbase = slab + d * PLANE;

    // ---- burst phase: 24 independent loads, no consumers interleaved ----
    float4 xr[10], tr[10];
    #pragma unroll
    for (int r = 0; r < 10; ++r) {
        int h = h0 + r - 1;                      // clamp only at volume edges
        h = (h < 0) ? 0 : ((h > Hn - 1) ? Hn - 1 : h);
        const int idx = pbase + h * ROW + w4;
        xr[r] = X[idx];
        tr[r] = T[idx];
    }
    // d-halo: 512 float4 u-values (2 planes x 8 h x 32 w4), 2 per thread
    float4 hx[2], htl[2];
    int hwr[2];
    #pragma unroll
    for (int k = 0; k < 2; ++k) {
        const int p    = tid + k * 256;          // [0,512)
        const int side = p >> 8;                 // 0: d0-1, 1: d0+8
        const int hh   = (p >> 5) & 7;
        const int ww   = p & 31;
        int dh = dt * 8 + (side ? 8 : -1);
        dh = (dh < 0) ? 0 : ((dh > Dn - 1) ? Dn - 1 : dh);  // one-sided at edges
        const int idx = slab + dh * PLANE + (h0 + hh) * ROW + ww;
        hx[k]  = X[idx];
        htl[k] = T[idx];
        hwr[k] = (side ? 9 : 0) * (8 * 32) + hh * 32 + ww;  // f4 idx in [10][8][32]
    }

    // ---- publish: u = x - t -> LDS tile [d-row 0..9][h 0..7][w4] ----
    __shared__ float4 uL[10][8][32];             // 40960 B exactly
    float4 u[10];
    #pragma unroll
    for (int r = 0; r < 10; ++r) u[r] = sub4(xr[r], tr[r]);
    #pragma unroll
    for (int hl = 0; hl < 8; ++hl) uL[dlow + 1][hl][w4] = u[hl + 1];
    #pragma unroll
    for (int k = 0; k < 2; ++k)
        ((float4*)uL)[hwr[k]] = sub4(hx[k], htl[k]);
    __syncthreads();                             // the ONE barrier

    // ---- compute phase: registers + LDS only ----
    const float sd2  = (d == 0 || d == Dn - 1) ? 1.0f : 0.25f;
    const float sw02 = (w4 == 0) ? 1.0f : 0.25f;
    const float sw32 = (w4 == 31) ? 1.0f : 0.25f;

    float acc0 = 0.0f, acc1 = 0.0f, acc2 = 0.0f;
    #pragma unroll
    for (int hl = 0; hl < 8; ++hl) {
        const int h = h0 + hl;
        const float sh2 = (h == 0 || h == Hn - 1) ? 1.0f : 0.25f;

        // D axis: u(d+1) - u(d-1) at this h, from LDS
        const float4 udp = uL[dlow + 2][hl][w4];
        const float4 udm = uL[dlow][hl][w4];
        { const float dx = udp.x - udm.x; acc1 = fmaf(dx * dx, sd2, acc1); }
        { const float dx = udp.y - udm.y; acc1 = fmaf(dx * dx, sd2, acc1); }
        { const float dx = udp.z - udm.z; acc1 = fmaf(dx * dx, sd2, acc1); }
        { const float dx = udp.w - udm.w; acc1 = fmaf(dx * dx, sd2, acc1); }

        // H axis: u(h+1) - u(h-1), register sliding window
        const float4 un = u[hl + 2];
        const float4 um = u[hl];
        { const float dx = un.x - um.x; acc0 = fmaf(dx * dx, sh2, acc0); }
        { const float dx = un.y - um.y; acc0 = fmaf(dx * dx, sh2, acc0); }
        { const float dx = un.z - um.z; acc0 = fmaf(dx * dx, sh2, acc0); }
        { const float dx = un.w - um.w; acc0 = fmaf(dx * dx, sh2, acc0); }

        // W axis: neighbors via shfl within 32-lane groups
        const float4 uc = u[hl + 1];
        const float ulw = __shfl_up(uc.w, 1, 32);
        const float urx = __shfl_down(uc.x, 1, 32);
        const float ul = (w4 == 0)  ? uc.x : ulw;
        const float ur = (w4 == 31) ? uc.w : urx;
        { const float dx = uc.y - ul;   acc2 = fmaf(dx * dx, sw02, acc2); }
        { const float dx = uc.z - uc.x; acc2 = fmaf(dx * dx, 0.25f, acc2); }
        { const float dx = uc.w - uc.y; acc2 = fmaf(dx * dx, 0.25f, acc2); }
        { const float dx = ur - uc.z;   acc2 = fmaf(dx * dx, sw32, acc2); }
    }

    float acc = (acc0 + acc1) + acc2;

    // wave (64-lane) reduction
    for (int off = 32; off > 0; off >>= 1)
        acc += __shfl_down(acc, off, 64);

    // reuse the LDS tile for cross-wave scratch (keeps LDS at 40960B)
    __syncthreads();                             // all uL reads done
    float* wsum = (float*)&uL[0][0][0];
    const int lane = tid & 63;
    const int wid = tid >> 6;
    if (lane == 0) wsum[wid] = acc;
    __syncthreads();
    if (tid == 0) {
        double bsum = (double)wsum[0] + (double)wsum[1] +
                      (double)wsum[2] + (double)wsum[3];
        partials[blockIdx.x] = bsum;
    }
}

__global__ __launch_bounds__(256) void gradloss_reduce(
        const double* __restrict__ partials, float* __restrict__ out, int n) {
    double a = 0.0;
    for (int i = threadIdx.x; i < n; i += 256) a += partials[i];
    for (int off = 32; off > 0; off >>= 1)
        a += __shfl_down(a, off, 64);
    __shared__ double sh[4];
    const int lane = threadIdx.x & 63;
    const int wid = threadIdx.x >> 6;
    if (lane == 0) sh[wid] = a;
    __syncthreads();
    if (threadIdx.x == 0) {
        double tot = sh[0] + sh[1] + sh[2] + sh[3];
        out[0] = (float)(tot / 8388608.0);  // / (B*D*H*W)
    }
}

extern "C" void kernel_launch(void* const* d_in, const int* in_sizes, int n_in,
                              void* d_out, int out_size, void* d_ws, size_t ws_size,
                              hipStream_t stream) {
    const float* x = (const float*)d_in[0];
    const float* t = (const float*)d_in[1];
    float* out = (float*)d_out;
    double* partials = (double*)d_ws;  // NBLOCKS * 8 B = 32 KiB of d_ws

    gradloss_main<<<NBLOCKS, NTHREADS, 0, stream>>>(x, t, partials);
    gradloss_reduce<<<1, 256, 0, stream>>>(partials, out, NBLOCKS);
}